// Round 1
// baseline (1609.006 us; speedup 1.0000x reference)
//
#include <hip/hip_runtime.h>

#define N_NODES   100000
#define N_EDGES   1600000
#define EDGE_DIM  32
#define NODE_DIM  128
#define GLOBAL_DIM 32
#define IN_DIM    224   // 32 rec + 32 send + 128 node + 32 glob
#define HIDDEN    256
#define OUT_DIM   128

// ---------------------------------------------------------------------------
// Kernel 1: edge scatter. One thread per (edge, 4-float chunk): 8 threads/edge.
// Reads are fully coalesced (64 lanes cover 8 edges x 128B contiguous).
// Atomic adds into rec_agg/send_agg (25.6 MB total, L2-resident).
// ---------------------------------------------------------------------------
__global__ __launch_bounds__(256) void scatter_kernel(
    const float* __restrict__ edge,
    const int*   __restrict__ snd,
    const int*   __restrict__ rcv,
    float*       __restrict__ rec_agg,
    float*       __restrict__ send_agg)
{
    int idx = blockIdx.x * 256 + threadIdx.x;
    int e = idx >> 3;
    if (e >= N_EDGES) return;
    int c = (idx & 7) * 4;

    float4 v = *(const float4*)&edge[(size_t)e * EDGE_DIM + c];
    int r = rcv[e];
    int s = snd[e];

    float* rp = &rec_agg[(size_t)r * EDGE_DIM + c];
    float* sp = &send_agg[(size_t)s * EDGE_DIM + c];
    atomicAdd(rp + 0, v.x);
    atomicAdd(rp + 1, v.y);
    atomicAdd(rp + 2, v.z);
    atomicAdd(rp + 3, v.w);
    atomicAdd(sp + 0, v.x);
    atomicAdd(sp + 1, v.y);
    atomicAdd(sp + 2, v.z);
    atomicAdd(sp + 3, v.w);
}

// ---------------------------------------------------------------------------
// Kernel 2: fused 2-layer MLP. 32 nodes per block, 256 threads.
// feats tile [32][224] staged in LDS (28 KB); h [32][256(+pad)] in LDS (32.5 KB).
// Layer 1: thread owns 4 hidden cols x 8 nodes (32 acc regs); feats reads are
// wave-uniform LDS broadcasts via ds_read_b128; W1 reads coalesced (L2-hot).
// Layer 2: thread owns 2 out cols x 8 nodes.
// ---------------------------------------------------------------------------
__global__ __launch_bounds__(256) void mlp_kernel(
    const float* __restrict__ rec,
    const float* __restrict__ send,
    const float* __restrict__ node,
    const float* __restrict__ glob,
    const float* __restrict__ W1,
    const float* __restrict__ b1,
    const float* __restrict__ W2,
    const float* __restrict__ b2,
    float*       __restrict__ out)
{
    __shared__ float sfeat[32][IN_DIM];      // 28 KB
    __shared__ float sh[32][HIDDEN + 4];     // 32.5 KB, stride 260 (1040B, 16B-aligned)

    const int tid  = threadIdx.x;
    const int base = blockIdx.x * 32;

    // ---- stage feats tile ----
    for (int idx = tid; idx < 32 * IN_DIM; idx += 256) {
        int n = idx / IN_DIM;
        int k = idx - n * IN_DIM;
        int g = base + n;
        float v;
        if (k < 32)       v = rec [(size_t)g * EDGE_DIM + k];
        else if (k < 64)  v = send[(size_t)g * EDGE_DIM + (k - 32)];
        else if (k < 192) v = node[(size_t)g * NODE_DIM + (k - 64)];
        else              v = glob[k - 192];
        sfeat[n][k] = v;
    }
    __syncthreads();

    const int c  = tid & 63;   // column base (wave-varying, coalesced W reads)
    const int nh = tid >> 6;   // node group 0..3 (wave-uniform -> LDS broadcast)

    // ---- layer 1: h = relu(feats @ W1 + b1) ----
    float acc[8][4];
    #pragma unroll
    for (int q = 0; q < 4; ++q) {
        float bv = b1[c + 64 * q];
        #pragma unroll
        for (int n = 0; n < 8; ++n) acc[n][q] = bv;
    }

    for (int k = 0; k < IN_DIM; k += 4) {
        float4 f[8];
        #pragma unroll
        for (int n = 0; n < 8; ++n)
            f[n] = *(const float4*)&sfeat[nh * 8 + n][k];
        float w[4][4];
        #pragma unroll
        for (int kk = 0; kk < 4; ++kk)
            #pragma unroll
            for (int q = 0; q < 4; ++q)
                w[kk][q] = W1[(size_t)(k + kk) * HIDDEN + c + 64 * q];
        #pragma unroll
        for (int n = 0; n < 8; ++n) {
            #pragma unroll
            for (int q = 0; q < 4; ++q) {
                float a = acc[n][q];
                a = fmaf(f[n].x, w[0][q], a);
                a = fmaf(f[n].y, w[1][q], a);
                a = fmaf(f[n].z, w[2][q], a);
                a = fmaf(f[n].w, w[3][q], a);
                acc[n][q] = a;
            }
        }
    }

    #pragma unroll
    for (int n = 0; n < 8; ++n)
        #pragma unroll
        for (int q = 0; q < 4; ++q)
            sh[nh * 8 + n][c + 64 * q] = fmaxf(acc[n][q], 0.0f);
    __syncthreads();

    // ---- layer 2: out = h @ W2 + b2 ----
    float acc2[8][2];
    #pragma unroll
    for (int q = 0; q < 2; ++q) {
        float bv = b2[c + 64 * q];
        #pragma unroll
        for (int n = 0; n < 8; ++n) acc2[n][q] = bv;
    }

    for (int k = 0; k < HIDDEN; k += 4) {
        float4 h4[8];
        #pragma unroll
        for (int n = 0; n < 8; ++n)
            h4[n] = *(const float4*)&sh[nh * 8 + n][k];
        float w2[4][2];
        #pragma unroll
        for (int kk = 0; kk < 4; ++kk)
            #pragma unroll
            for (int q = 0; q < 2; ++q)
                w2[kk][q] = W2[(size_t)(k + kk) * OUT_DIM + c + 64 * q];
        #pragma unroll
        for (int n = 0; n < 8; ++n) {
            #pragma unroll
            for (int q = 0; q < 2; ++q) {
                float a = acc2[n][q];
                a = fmaf(h4[n].x, w2[0][q], a);
                a = fmaf(h4[n].y, w2[1][q], a);
                a = fmaf(h4[n].z, w2[2][q], a);
                a = fmaf(h4[n].w, w2[3][q], a);
                acc2[n][q] = a;
            }
        }
    }

    #pragma unroll
    for (int n = 0; n < 8; ++n)
        #pragma unroll
        for (int q = 0; q < 2; ++q)
            out[(size_t)(base + nh * 8 + n) * OUT_DIM + c + 64 * q] = acc2[n][q];
}

extern "C" void kernel_launch(void* const* d_in, const int* in_sizes, int n_in,
                              void* d_out, int out_size, void* d_ws, size_t ws_size,
                              hipStream_t stream) {
    const float* edge = (const float*)d_in[0];
    const int*   snd  = (const int*)  d_in[1];
    const int*   rcv  = (const int*)  d_in[2];
    const float* node = (const float*)d_in[3];
    const float* glob = (const float*)d_in[4];
    const float* W1   = (const float*)d_in[5];
    const float* b1   = (const float*)d_in[6];
    const float* W2   = (const float*)d_in[7];
    const float* b2   = (const float*)d_in[8];
    float* out = (float*)d_out;

    float* rec_agg  = (float*)d_ws;
    float* send_agg = rec_agg + (size_t)N_NODES * EDGE_DIM;

    // zero the aggregation buffers every call (atomic accumulation target)
    hipMemsetAsync(d_ws, 0, (size_t)2 * N_NODES * EDGE_DIM * sizeof(float), stream);

    // scatter: 1.6M edges * 8 chunk-threads = 12.8M threads
    int scatter_blocks = (N_EDGES * 8 + 255) / 256;  // 50000
    scatter_kernel<<<scatter_blocks, 256, 0, stream>>>(edge, snd, rcv, rec_agg, send_agg);

    // fused MLP: 100000 / 32 = 3125 blocks exactly
    mlp_kernel<<<N_NODES / 32, 256, 0, stream>>>(rec_agg, send_agg, node, glob,
                                                 W1, b1, W2, b2, out);
}

// Round 2
// 951.721 us; speedup vs baseline: 1.6906x; 1.6906x over previous
//
#include <hip/hip_runtime.h>

#define N_NODES   100000
#define N_EDGES   1600000
#define EDGE_DIM  32
#define NODE_DIM  128
#define IN_DIM    224   // 32 rec + 32 send + 128 node + 32 glob
#define HIDDEN    256
#define OUT_DIM   128
#define NCNT      (2 * N_NODES)        // rec counters then send counters
#define SCAN_BLK  1024                 // elements per scan block
#define NSCAN     ((NCNT + SCAN_BLK - 1) / SCAN_BLK)   // 196

// ws layout (int32 words):
//  cnt  [0,       200000)
//  off  [200000,  400001)   exclusive prefix over cnt, +1 sentinel
//  pos  [400001,  600001)   running cursors (copy of off)
//  eids [600001,  3800001)  edge-id lists: rec lists then send lists
#define WS_CNT   0
#define WS_OFF   200000
#define WS_POS   400001
#define WS_EIDS  600001

// ---------------------------------------------------------------------------
// Histogram: 2 int atomics per edge (6250 blocks x 256)
// ---------------------------------------------------------------------------
__global__ __launch_bounds__(256) void hist_kernel(
    const int* __restrict__ snd, const int* __restrict__ rcv, int* __restrict__ cnt)
{
    int e = blockIdx.x * 256 + threadIdx.x;
    if (e >= N_EDGES) return;
    atomicAdd(&cnt[rcv[e]], 1);
    atomicAdd(&cnt[N_NODES + snd[e]], 1);
}

// ---------------------------------------------------------------------------
// Scan pass 1: per-block (1024-elem) local exclusive scan -> off, block sums
// ---------------------------------------------------------------------------
__global__ __launch_bounds__(256) void scan1_kernel(
    const int* __restrict__ cnt, int* __restrict__ off, int* __restrict__ bsum)
{
    __shared__ int ts[256];
    const int t = threadIdx.x;
    const int base = blockIdx.x * SCAN_BLK + t * 4;

    int v[4], s = 0;
    #pragma unroll
    for (int j = 0; j < 4; ++j) {
        int idx = base + j;
        v[j] = (idx < NCNT) ? cnt[idx] : 0;
        s += v[j];
    }
    ts[t] = s;
    __syncthreads();
    for (int d = 1; d < 256; d <<= 1) {
        int x = (t >= d) ? ts[t - d] : 0;
        __syncthreads();
        ts[t] += x;
        __syncthreads();
    }
    int run = ts[t] - s;   // exclusive prefix of this thread's chunk
    #pragma unroll
    for (int j = 0; j < 4; ++j) {
        int idx = base + j;
        if (idx < NCNT) off[idx] = run;
        run += v[j];
    }
    if (t == 255) bsum[blockIdx.x] = ts[255];
}

// ---------------------------------------------------------------------------
// Scan pass 2: single block scans the 196 block sums (exclusive, in place)
// ---------------------------------------------------------------------------
__global__ __launch_bounds__(256) void scan2_kernel(int* __restrict__ bsum)
{
    __shared__ int ts[256];
    const int t = threadIdx.x;
    int v = (t < NSCAN) ? bsum[t] : 0;
    ts[t] = v;
    __syncthreads();
    for (int d = 1; d < 256; d <<= 1) {
        int x = (t >= d) ? ts[t - d] : 0;
        __syncthreads();
        ts[t] += x;
        __syncthreads();
    }
    if (t < NSCAN) bsum[t] = ts[t] - v;
}

// ---------------------------------------------------------------------------
// Scan pass 3: add block offsets, write sentinel, init cursors
// ---------------------------------------------------------------------------
__global__ __launch_bounds__(256) void scan3_kernel(
    int* __restrict__ off, const int* __restrict__ bsum, int* __restrict__ pos)
{
    const int t = threadIdx.x;
    const int base = blockIdx.x * SCAN_BLK + t * 4;
    int bo = bsum[blockIdx.x];
    #pragma unroll
    for (int j = 0; j < 4; ++j) {
        int idx = base + j;
        if (idx < NCNT) {
            int o = off[idx] + bo;
            off[idx] = o;
            pos[idx] = o;
        }
    }
    if (blockIdx.x == 0 && t == 0) off[NCNT] = 2 * N_EDGES;
}

// ---------------------------------------------------------------------------
// Fill: scatter edge ids into per-node contiguous lists (2 int atomics/edge)
// ---------------------------------------------------------------------------
__global__ __launch_bounds__(256) void fill_kernel(
    const int* __restrict__ snd, const int* __restrict__ rcv,
    int* __restrict__ pos, int* __restrict__ eids)
{
    int e = blockIdx.x * 256 + threadIdx.x;
    if (e >= N_EDGES) return;
    int p = atomicAdd(&pos[rcv[e]], 1);
    eids[p] = e;
    int q = atomicAdd(&pos[N_NODES + snd[e]], 1);
    eids[q] = e;
}

// ---------------------------------------------------------------------------
// Fused gather + 2-layer MLP. 32 nodes/block, 256 threads.
// Gather: 8-lane group per node sums its edge rows (128B coalesced segments,
// edge buffer is L3-resident) straight into LDS feats. No atomics.
// ---------------------------------------------------------------------------
__global__ __launch_bounds__(256) void mlp_kernel(
    const float* __restrict__ edge,
    const int*   __restrict__ off,
    const int*   __restrict__ eids,
    const float* __restrict__ node,
    const float* __restrict__ glob,
    const float* __restrict__ W1,
    const float* __restrict__ b1,
    const float* __restrict__ W2,
    const float* __restrict__ b2,
    float*       __restrict__ out)
{
    __shared__ float sfeat[32][IN_DIM];      // 28 KB
    __shared__ float sh[32][HIDDEN + 4];     // 32.5 KB

    const int tid  = threadIdx.x;
    const int base = blockIdx.x * 32;

    // ---- gather rec/send aggregates for this tile's 32 nodes ----
    {
        const int g   = tid >> 3;           // node within tile
        const int sub = tid & 7;            // 4-float chunk
        const int n   = base + g;

        float4 ar = make_float4(0.f, 0.f, 0.f, 0.f);
        int s0 = off[n], e0 = off[n + 1];
        for (int i = s0; i < e0; ++i) {
            int eid = eids[i];
            float4 v = *(const float4*)&edge[(size_t)eid * EDGE_DIM + sub * 4];
            ar.x += v.x; ar.y += v.y; ar.z += v.z; ar.w += v.w;
        }
        float4 as = make_float4(0.f, 0.f, 0.f, 0.f);
        int s1 = off[N_NODES + n], e1 = off[N_NODES + n + 1];
        for (int i = s1; i < e1; ++i) {
            int eid = eids[i];
            float4 v = *(const float4*)&edge[(size_t)eid * EDGE_DIM + sub * 4];
            as.x += v.x; as.y += v.y; as.z += v.z; as.w += v.w;
        }
        *(float4*)&sfeat[g][sub * 4]      = ar;
        *(float4*)&sfeat[g][32 + sub * 4] = as;
    }

    // ---- stage node attrs + globals (cols 64..223) ----
    for (int idx = tid; idx < 32 * 160; idx += 256) {
        int n = idx / 160;
        int k = idx - n * 160;
        sfeat[n][64 + k] = (k < 128) ? node[(size_t)(base + n) * NODE_DIM + k]
                                     : glob[k - 128];
    }
    __syncthreads();

    const int c  = tid & 63;   // column base (coalesced W reads)
    const int nh = tid >> 6;   // node group 0..3 (wave-uniform -> LDS broadcast)

    // ---- layer 1: h = relu(feats @ W1 + b1) ----
    float acc[8][4];
    #pragma unroll
    for (int q = 0; q < 4; ++q) {
        float bv = b1[c + 64 * q];
        #pragma unroll
        for (int n = 0; n < 8; ++n) acc[n][q] = bv;
    }

    for (int k = 0; k < IN_DIM; k += 4) {
        float4 f[8];
        #pragma unroll
        for (int n = 0; n < 8; ++n)
            f[n] = *(const float4*)&sfeat[nh * 8 + n][k];
        float w[4][4];
        #pragma unroll
        for (int kk = 0; kk < 4; ++kk)
            #pragma unroll
            for (int q = 0; q < 4; ++q)
                w[kk][q] = W1[(size_t)(k + kk) * HIDDEN + c + 64 * q];
        #pragma unroll
        for (int n = 0; n < 8; ++n) {
            #pragma unroll
            for (int q = 0; q < 4; ++q) {
                float a = acc[n][q];
                a = fmaf(f[n].x, w[0][q], a);
                a = fmaf(f[n].y, w[1][q], a);
                a = fmaf(f[n].z, w[2][q], a);
                a = fmaf(f[n].w, w[3][q], a);
                acc[n][q] = a;
            }
        }
    }

    #pragma unroll
    for (int n = 0; n < 8; ++n)
        #pragma unroll
        for (int q = 0; q < 4; ++q)
            sh[nh * 8 + n][c + 64 * q] = fmaxf(acc[n][q], 0.0f);
    __syncthreads();

    // ---- layer 2: out = h @ W2 + b2 ----
    float acc2[8][2];
    #pragma unroll
    for (int q = 0; q < 2; ++q) {
        float bv = b2[c + 64 * q];
        #pragma unroll
        for (int n = 0; n < 8; ++n) acc2[n][q] = bv;
    }

    for (int k = 0; k < HIDDEN; k += 4) {
        float4 h4[8];
        #pragma unroll
        for (int n = 0; n < 8; ++n)
            h4[n] = *(const float4*)&sh[nh * 8 + n][k];
        float w2[4][2];
        #pragma unroll
        for (int kk = 0; kk < 4; ++kk)
            #pragma unroll
            for (int q = 0; q < 2; ++q)
                w2[kk][q] = W2[(size_t)(k + kk) * OUT_DIM + c + 64 * q];
        #pragma unroll
        for (int n = 0; n < 8; ++n) {
            #pragma unroll
            for (int q = 0; q < 2; ++q) {
                float a = acc2[n][q];
                a = fmaf(h4[n].x, w2[0][q], a);
                a = fmaf(h4[n].y, w2[1][q], a);
                a = fmaf(h4[n].z, w2[2][q], a);
                a = fmaf(h4[n].w, w2[3][q], a);
                acc2[n][q] = a;
            }
        }
    }

    #pragma unroll
    for (int n = 0; n < 8; ++n)
        #pragma unroll
        for (int q = 0; q < 2; ++q)
            out[(size_t)(base + nh * 8 + n) * OUT_DIM + c + 64 * q] = acc2[n][q];
}

extern "C" void kernel_launch(void* const* d_in, const int* in_sizes, int n_in,
                              void* d_out, int out_size, void* d_ws, size_t ws_size,
                              hipStream_t stream) {
    const float* edge = (const float*)d_in[0];
    const int*   snd  = (const int*)  d_in[1];
    const int*   rcv  = (const int*)  d_in[2];
    const float* node = (const float*)d_in[3];
    const float* glob = (const float*)d_in[4];
    const float* W1   = (const float*)d_in[5];
    const float* b1   = (const float*)d_in[6];
    const float* W2   = (const float*)d_in[7];
    const float* b2   = (const float*)d_in[8];
    float* out = (float*)d_out;

    int* ws   = (int*)d_ws;
    int* cnt  = ws + WS_CNT;
    int* off  = ws + WS_OFF;
    int* pos  = ws + WS_POS;
    int* eids = ws + WS_EIDS;
    int* bsum = ws + WS_EIDS + 2 * N_EDGES;   // 196 ints

    // zero the histogram counters each call
    hipMemsetAsync(cnt, 0, NCNT * sizeof(int), stream);

    const int eblocks = (N_EDGES + 255) / 256;   // 6250
    hist_kernel <<<eblocks, 256, 0, stream>>>(snd, rcv, cnt);
    scan1_kernel<<<NSCAN,   256, 0, stream>>>(cnt, off, bsum);
    scan2_kernel<<<1,       256, 0, stream>>>(bsum);
    scan3_kernel<<<NSCAN,   256, 0, stream>>>(off, bsum, pos);
    fill_kernel <<<eblocks, 256, 0, stream>>>(snd, rcv, pos, eids);

    mlp_kernel<<<N_NODES / 32, 256, 0, stream>>>(edge, off, eids, node, glob,
                                                 W1, b1, W2, b2, out);
}

// Round 3
// 893.094 us; speedup vs baseline: 1.8016x; 1.0656x over previous
//
#include <hip/hip_runtime.h>

#define N_NODES   100000
#define N_EDGES   1600000
#define EDGE_DIM  32
#define NODE_DIM  128
#define IN_DIM    224   // 32 rec + 32 send + 128 node + 32 glob
#define HIDDEN    256
#define OUT_DIM   128
#define NCNT      (2 * N_NODES)        // rec counters then send counters
#define SCAN_BLK  1024                 // elements per scan block
#define NSCAN     ((NCNT + SCAN_BLK - 1) / SCAN_BLK)   // 196

// ws layout:
//  agg   float[200000*32]          (25.6 MB)  rec rows then send rows
//  cnt   int[200000]
//  off   int[200001]
//  pos   int[200001]
//  eids  int[3200000]
//  bsum  int[196]
#define WS_AGG_F   0
#define WS_CNT_I   (NCNT * EDGE_DIM)            // in int words (float==int size)
#define WS_OFF_I   (WS_CNT_I + NCNT)
#define WS_POS_I   (WS_OFF_I + NCNT + 1)
#define WS_EIDS_I  (WS_POS_I + NCNT + 1)
#define WS_BSUM_I  (WS_EIDS_I + 2 * N_EDGES)

// ---------------------------------------------------------------------------
// Histogram: 2 int atomics per edge
// ---------------------------------------------------------------------------
__global__ __launch_bounds__(256) void hist_kernel(
    const int* __restrict__ snd, const int* __restrict__ rcv, int* __restrict__ cnt)
{
    int e = blockIdx.x * 256 + threadIdx.x;
    if (e >= N_EDGES) return;
    atomicAdd(&cnt[rcv[e]], 1);
    atomicAdd(&cnt[N_NODES + snd[e]], 1);
}

// ---------------------------------------------------------------------------
// Scan pass 1: per-block (1024-elem) local exclusive scan -> off, block sums
// ---------------------------------------------------------------------------
__global__ __launch_bounds__(256) void scan1_kernel(
    const int* __restrict__ cnt, int* __restrict__ off, int* __restrict__ bsum)
{
    __shared__ int ts[256];
    const int t = threadIdx.x;
    const int base = blockIdx.x * SCAN_BLK + t * 4;

    int v[4], s = 0;
    #pragma unroll
    for (int j = 0; j < 4; ++j) {
        int idx = base + j;
        v[j] = (idx < NCNT) ? cnt[idx] : 0;
        s += v[j];
    }
    ts[t] = s;
    __syncthreads();
    for (int d = 1; d < 256; d <<= 1) {
        int x = (t >= d) ? ts[t - d] : 0;
        __syncthreads();
        ts[t] += x;
        __syncthreads();
    }
    int run = ts[t] - s;
    #pragma unroll
    for (int j = 0; j < 4; ++j) {
        int idx = base + j;
        if (idx < NCNT) off[idx] = run;
        run += v[j];
    }
    if (t == 255) bsum[blockIdx.x] = ts[255];
}

// ---------------------------------------------------------------------------
// Scan pass 2+3 fused: every block redundantly scans the 196 block sums,
// picks its own exclusive offset, then finalizes off and inits pos.
// ---------------------------------------------------------------------------
__global__ __launch_bounds__(256) void scan23_kernel(
    int* __restrict__ off, const int* __restrict__ bsum, int* __restrict__ pos)
{
    __shared__ int ts[256];
    __shared__ int sboff;
    const int t = threadIdx.x;
    int v = (t < NSCAN) ? bsum[t] : 0;
    ts[t] = v;
    __syncthreads();
    for (int d = 1; d < 256; d <<= 1) {
        int x = (t >= d) ? ts[t - d] : 0;
        __syncthreads();
        ts[t] += x;
        __syncthreads();
    }
    if (t == (int)blockIdx.x) sboff = ts[t] - v;   // exclusive prefix at this block
    __syncthreads();
    const int bo = sboff;

    const int base = blockIdx.x * SCAN_BLK + t * 4;
    #pragma unroll
    for (int j = 0; j < 4; ++j) {
        int idx = base + j;
        if (idx < NCNT) {
            int o = off[idx] + bo;
            off[idx] = o;
            pos[idx] = o;
        }
    }
    if (blockIdx.x == 0 && t == 0) off[NCNT] = 2 * N_EDGES;
}

// ---------------------------------------------------------------------------
// Fill: scatter edge ids into per-node contiguous lists (2 int atomics/edge)
// ---------------------------------------------------------------------------
__global__ __launch_bounds__(256) void fill_kernel(
    const int* __restrict__ snd, const int* __restrict__ rcv,
    int* __restrict__ pos, int* __restrict__ eids)
{
    int e = blockIdx.x * 256 + threadIdx.x;
    if (e >= N_EDGES) return;
    int p = atomicAdd(&pos[rcv[e]], 1);
    eids[p] = e;
    int q = atomicAdd(&pos[N_NODES + snd[e]], 1);
    eids[q] = e;
}

// ---------------------------------------------------------------------------
// Gather: one 8-lane group per segment (node x {rec,send}); sums edge rows.
// Tiny LDS footprint -> full occupancy; random-row latency hidden by TLP.
// ---------------------------------------------------------------------------
__global__ __launch_bounds__(256) void gather_kernel(
    const float* __restrict__ edge,
    const int*   __restrict__ off,
    const int*   __restrict__ eids,
    float*       __restrict__ agg)
{
    int seg = blockIdx.x * 32 + (threadIdx.x >> 3);
    if (seg >= NCNT) return;
    const int sub = threadIdx.x & 7;

    int s = off[seg], e = off[seg + 1];
    float4 a = make_float4(0.f, 0.f, 0.f, 0.f);
    for (int i = s; i < e; ++i) {
        int eid = eids[i];   // same addr across the 8 lanes -> broadcast hit
        float4 v = *(const float4*)&edge[(size_t)eid * EDGE_DIM + sub * 4];
        a.x += v.x; a.y += v.y; a.z += v.z; a.w += v.w;
    }
    *(float4*)&agg[(size_t)seg * EDGE_DIM + sub * 4] = a;
}

// ---------------------------------------------------------------------------
// MLP: 16 nodes/block, 256 threads. LDS 31 KB -> 5 blocks/CU (20 waves).
// Thread owns 4 contiguous W1 cols (float4 W loads) x 4 nodes, then
// 2 contiguous W2 cols (float2) x 4 nodes. Feats via LDS broadcast.
// ---------------------------------------------------------------------------
__global__ __launch_bounds__(256) void mlp_kernel(
    const float* __restrict__ agg,
    const float* __restrict__ node,
    const float* __restrict__ glob,
    const float* __restrict__ W1,
    const float* __restrict__ b1,
    const float* __restrict__ W2,
    const float* __restrict__ b2,
    float*       __restrict__ out)
{
    __shared__ float sfeat[16][IN_DIM];      // 14 KB
    __shared__ float sh[16][HIDDEN + 4];     // 16.6 KB

    const int tid  = threadIdx.x;
    const int base = blockIdx.x * 16;

    // ---- stage feats tile: 16 nodes x 56 float4s ----
    for (int f = tid; f < 16 * 56; f += 256) {
        int n  = f / 56;
        int c4 = f - n * 56;
        float4 v;
        if (c4 < 8)
            v = *(const float4*)&agg[((size_t)(base + n)) * EDGE_DIM + c4 * 4];
        else if (c4 < 16)
            v = *(const float4*)&agg[((size_t)(N_NODES + base + n)) * EDGE_DIM + (c4 - 8) * 4];
        else if (c4 < 48)
            v = *(const float4*)&node[(size_t)(base + n) * NODE_DIM + (c4 - 16) * 4];
        else
            v = *(const float4*)&glob[(c4 - 48) * 4];
        *(float4*)&sfeat[n][c4 * 4] = v;
    }
    __syncthreads();

    const int c  = tid & 63;   // col group: W1 cols 4c..4c+3, W2 cols 2c..2c+1
    const int nh = tid >> 6;   // node group: nodes nh*4..nh*4+3 (wave-uniform)

    // ---- layer 1: h = relu(feats @ W1 + b1) ----
    float4 bv1 = *(const float4*)&b1[4 * c];
    float acc[4][4];
    #pragma unroll
    for (int n = 0; n < 4; ++n) {
        acc[n][0] = bv1.x; acc[n][1] = bv1.y; acc[n][2] = bv1.z; acc[n][3] = bv1.w;
    }

    for (int k = 0; k < IN_DIM; k += 4) {
        float4 f[4];
        #pragma unroll
        for (int n = 0; n < 4; ++n)
            f[n] = *(const float4*)&sfeat[nh * 4 + n][k];   // broadcast
        float4 w[4];
        #pragma unroll
        for (int kk = 0; kk < 4; ++kk)
            w[kk] = *(const float4*)&W1[(size_t)(k + kk) * HIDDEN + 4 * c];  // coalesced 1KB/row
        #pragma unroll
        for (int n = 0; n < 4; ++n) {
            float fv[4] = {f[n].x, f[n].y, f[n].z, f[n].w};
            #pragma unroll
            for (int kk = 0; kk < 4; ++kk) {
                acc[n][0] = fmaf(fv[kk], w[kk].x, acc[n][0]);
                acc[n][1] = fmaf(fv[kk], w[kk].y, acc[n][1]);
                acc[n][2] = fmaf(fv[kk], w[kk].z, acc[n][2]);
                acc[n][3] = fmaf(fv[kk], w[kk].w, acc[n][3]);
            }
        }
    }

    #pragma unroll
    for (int n = 0; n < 4; ++n) {
        float4 r;
        r.x = fmaxf(acc[n][0], 0.f);
        r.y = fmaxf(acc[n][1], 0.f);
        r.z = fmaxf(acc[n][2], 0.f);
        r.w = fmaxf(acc[n][3], 0.f);
        *(float4*)&sh[nh * 4 + n][4 * c] = r;
    }
    __syncthreads();

    // ---- layer 2: out = h @ W2 + b2 ----
    float2 bv2 = *(const float2*)&b2[2 * c];
    float acc2[4][2];
    #pragma unroll
    for (int n = 0; n < 4; ++n) { acc2[n][0] = bv2.x; acc2[n][1] = bv2.y; }

    for (int k = 0; k < HIDDEN; k += 4) {
        float4 h4[4];
        #pragma unroll
        for (int n = 0; n < 4; ++n)
            h4[n] = *(const float4*)&sh[nh * 4 + n][k];   // broadcast
        float2 w2[4];
        #pragma unroll
        for (int kk = 0; kk < 4; ++kk)
            w2[kk] = *(const float2*)&W2[(size_t)(k + kk) * OUT_DIM + 2 * c];  // coalesced
        #pragma unroll
        for (int n = 0; n < 4; ++n) {
            float hv[4] = {h4[n].x, h4[n].y, h4[n].z, h4[n].w};
            #pragma unroll
            for (int kk = 0; kk < 4; ++kk) {
                acc2[n][0] = fmaf(hv[kk], w2[kk].x, acc2[n][0]);
                acc2[n][1] = fmaf(hv[kk], w2[kk].y, acc2[n][1]);
            }
        }
    }

    #pragma unroll
    for (int n = 0; n < 4; ++n) {
        float2 r; r.x = acc2[n][0]; r.y = acc2[n][1];
        *(float2*)&out[(size_t)(base + nh * 4 + n) * OUT_DIM + 2 * c] = r;
    }
}

extern "C" void kernel_launch(void* const* d_in, const int* in_sizes, int n_in,
                              void* d_out, int out_size, void* d_ws, size_t ws_size,
                              hipStream_t stream) {
    const float* edge = (const float*)d_in[0];
    const int*   snd  = (const int*)  d_in[1];
    const int*   rcv  = (const int*)  d_in[2];
    const float* node = (const float*)d_in[3];
    const float* glob = (const float*)d_in[4];
    const float* W1   = (const float*)d_in[5];
    const float* b1   = (const float*)d_in[6];
    const float* W2   = (const float*)d_in[7];
    const float* b2   = (const float*)d_in[8];
    float* out = (float*)d_out;

    float* agg = (float*)d_ws;
    int*   wsi = (int*)d_ws;
    int* cnt  = wsi + WS_CNT_I;
    int* off  = wsi + WS_OFF_I;
    int* pos  = wsi + WS_POS_I;
    int* eids = wsi + WS_EIDS_I;
    int* bsum = wsi + WS_BSUM_I;

    hipMemsetAsync(cnt, 0, NCNT * sizeof(int), stream);

    const int eblocks = (N_EDGES + 255) / 256;   // 6250
    hist_kernel  <<<eblocks, 256, 0, stream>>>(snd, rcv, cnt);
    scan1_kernel <<<NSCAN,   256, 0, stream>>>(cnt, off, bsum);
    scan23_kernel<<<NSCAN,   256, 0, stream>>>(off, bsum, pos);
    fill_kernel  <<<eblocks, 256, 0, stream>>>(snd, rcv, pos, eids);

    gather_kernel<<<(NCNT + 31) / 32, 256, 0, stream>>>(edge, off, eids, agg);

    mlp_kernel<<<N_NODES / 16, 256, 0, stream>>>(agg, node, glob,
                                                 W1, b1, W2, b2, out);
}

// Round 4
// 680.637 us; speedup vs baseline: 2.3640x; 1.3121x over previous
//
#include <hip/hip_runtime.h>

#define N_NODES   100000
#define N_EDGES   1600000
#define EDGE_DIM  32
#define NODE_DIM  128
#define IN_DIM    224
#define HIDDEN    256
#define OUT_DIM   128
#define NCNT      (2 * N_NODES)
#define SCAN_BLK  1024
#define NSCAN     ((NCNT + SCAN_BLK - 1) / SCAN_BLK)   // 196

typedef float  float4v  __attribute__((ext_vector_type(4)));
typedef float  f32x4    __attribute__((ext_vector_type(4)));
typedef short  short8   __attribute__((ext_vector_type(8)));
typedef unsigned short ushort4v __attribute__((ext_vector_type(4)));

// ws layout in 4-byte words:
//  feats_bf ushort[100000*64]   -> words [0, 3200000)        (rec cols 0-31, send 32-63)
//  W1T      ushort[256*224]     -> words [3200000, 3228672)
//  W2T      ushort[128*256]     -> words [3228672, 3245056)
//  cnt      int[200000]
//  off      int[200001]
//  pos      int[200001]
//  eids     int[3200000]
//  bsum     int[196]
#define WS_FEATS_W 0
#define WS_W1T_W   3200000
#define WS_W2T_W   3228672
#define WS_CNT_W   3245056
#define WS_OFF_W   (WS_CNT_W + NCNT)
#define WS_POS_W   (WS_OFF_W + NCNT + 1)
#define WS_EIDS_W  (WS_POS_W + NCNT + 1)
#define WS_BSUM_W  (WS_EIDS_W + 2 * N_EDGES)

__device__ __forceinline__ unsigned short f2bf(float f) {
    unsigned int u = __float_as_uint(f);
    return (unsigned short)((u + 0x7fffu + ((u >> 16) & 1u)) >> 16);   // RNE
}

// ---------------------------------------------------------------------------
// Weight transpose + bf16 convert: W1T[n][k], W2T[o][k]
// ---------------------------------------------------------------------------
__global__ __launch_bounds__(256) void wcvt_kernel(
    const float* __restrict__ W1, const float* __restrict__ W2,
    unsigned short* __restrict__ W1T, unsigned short* __restrict__ W2T)
{
    int id = blockIdx.x * 256 + threadIdx.x;
    if (id < IN_DIM * HIDDEN) {               // 57344
        int n = id / IN_DIM, k = id - n * IN_DIM;
        W1T[id] = f2bf(W1[(size_t)k * HIDDEN + n]);
    } else {
        int id2 = id - IN_DIM * HIDDEN;
        if (id2 < HIDDEN * OUT_DIM) {         // 32768
            int o = id2 / HIDDEN, k = id2 - o * HIDDEN;
            W2T[id2] = f2bf(W2[(size_t)k * OUT_DIM + o]);
        }
    }
}

// ---------------------------------------------------------------------------
// Histogram: 2 int atomics per edge
// ---------------------------------------------------------------------------
__global__ __launch_bounds__(256) void hist_kernel(
    const int* __restrict__ snd, const int* __restrict__ rcv, int* __restrict__ cnt)
{
    int e = blockIdx.x * 256 + threadIdx.x;
    if (e >= N_EDGES) return;
    atomicAdd(&cnt[rcv[e]], 1);
    atomicAdd(&cnt[N_NODES + snd[e]], 1);
}

// ---------------------------------------------------------------------------
// Scan pass 1
// ---------------------------------------------------------------------------
__global__ __launch_bounds__(256) void scan1_kernel(
    const int* __restrict__ cnt, int* __restrict__ off, int* __restrict__ bsum)
{
    __shared__ int ts[256];
    const int t = threadIdx.x;
    const int base = blockIdx.x * SCAN_BLK + t * 4;

    int v[4], s = 0;
    #pragma unroll
    for (int j = 0; j < 4; ++j) {
        int idx = base + j;
        v[j] = (idx < NCNT) ? cnt[idx] : 0;
        s += v[j];
    }
    ts[t] = s;
    __syncthreads();
    for (int d = 1; d < 256; d <<= 1) {
        int x = (t >= d) ? ts[t - d] : 0;
        __syncthreads();
        ts[t] += x;
        __syncthreads();
    }
    int run = ts[t] - s;
    #pragma unroll
    for (int j = 0; j < 4; ++j) {
        int idx = base + j;
        if (idx < NCNT) off[idx] = run;
        run += v[j];
    }
    if (t == 255) bsum[blockIdx.x] = ts[255];
}

// ---------------------------------------------------------------------------
// Scan pass 2+3 fused
// ---------------------------------------------------------------------------
__global__ __launch_bounds__(256) void scan23_kernel(
    int* __restrict__ off, const int* __restrict__ bsum, int* __restrict__ pos)
{
    __shared__ int ts[256];
    __shared__ int sboff;
    const int t = threadIdx.x;
    int v = (t < NSCAN) ? bsum[t] : 0;
    ts[t] = v;
    __syncthreads();
    for (int d = 1; d < 256; d <<= 1) {
        int x = (t >= d) ? ts[t - d] : 0;
        __syncthreads();
        ts[t] += x;
        __syncthreads();
    }
    if (t == (int)blockIdx.x) sboff = ts[t] - v;
    __syncthreads();
    const int bo = sboff;

    const int base = blockIdx.x * SCAN_BLK + t * 4;
    #pragma unroll
    for (int j = 0; j < 4; ++j) {
        int idx = base + j;
        if (idx < NCNT) {
            int o = off[idx] + bo;
            off[idx] = o;
            pos[idx] = o;
        }
    }
    if (blockIdx.x == 0 && t == 0) off[NCNT] = 2 * N_EDGES;
}

// ---------------------------------------------------------------------------
// Fill edge-id lists
// ---------------------------------------------------------------------------
__global__ __launch_bounds__(256) void fill_kernel(
    const int* __restrict__ snd, const int* __restrict__ rcv,
    int* __restrict__ pos, int* __restrict__ eids)
{
    int e = blockIdx.x * 256 + threadIdx.x;
    if (e >= N_EDGES) return;
    int p = atomicAdd(&pos[rcv[e]], 1);
    eids[p] = e;
    int q = atomicAdd(&pos[N_NODES + snd[e]], 1);
    eids[q] = e;
}

// ---------------------------------------------------------------------------
// Gather: 8-lane group per segment; fp32 sums -> bf16 into feats buffer.
// feats_bf[node][0..31]=rec agg, [32..63]=send agg.
// ---------------------------------------------------------------------------
__global__ __launch_bounds__(256) void gather_kernel(
    const float* __restrict__ edge,
    const int*   __restrict__ off,
    const int*   __restrict__ eids,
    unsigned short* __restrict__ feats_bf)
{
    int seg = blockIdx.x * 32 + (threadIdx.x >> 3);
    if (seg >= NCNT) return;
    const int sub = threadIdx.x & 7;

    int s = off[seg], e = off[seg + 1];
    float4 a = make_float4(0.f, 0.f, 0.f, 0.f);
    for (int i = s; i < e; ++i) {
        int eid = eids[i];
        float4 v = *(const float4*)&edge[(size_t)eid * EDGE_DIM + sub * 4];
        a.x += v.x; a.y += v.y; a.z += v.z; a.w += v.w;
    }
    int nodeI = (seg < N_NODES) ? seg : (seg - N_NODES);
    int colB  = (seg < N_NODES) ? 0 : 32;
    ushort4v r;
    r.x = f2bf(a.x); r.y = f2bf(a.y); r.z = f2bf(a.z); r.w = f2bf(a.w);
    *(ushort4v*)&feats_bf[(size_t)nodeI * 64 + colB + sub * 4] = r;
}

// ---------------------------------------------------------------------------
// MFMA MLP: 64 nodes/block, 4 waves; wave w owns rows w*16..w*16+15.
// GEMM1: feats[64x224]bf16 @ W1T -> relu -> h LDS bf16; GEMM2 -> out fp32.
// A-frags: ds_read_b128 (lane: row=l&15, k=(l>>4)*8..+8).
// B-frags: global 16B loads from k-contiguous W-T rows (L1/L2-hot).
// ---------------------------------------------------------------------------
#define SFP 232   // sfeat LDS row stride in bf16 (464 B)
#define SHP 264   // h     LDS row stride in bf16 (528 B)

__global__ __launch_bounds__(256) void mlp_kernel(
    const unsigned short* __restrict__ feats_bf,
    const float* __restrict__ node,
    const float* __restrict__ glob,
    const unsigned short* __restrict__ W1T,
    const float* __restrict__ b1,
    const unsigned short* __restrict__ W2T,
    const float* __restrict__ b2,
    float*       __restrict__ out)
{
    __shared__ unsigned short sfeat[64][SFP];   // 29.0 KB
    __shared__ unsigned short sh[64][SHP];      // 33.0 KB

    const int tid  = threadIdx.x;
    const int base = blockIdx.x * 64;

    // ---- stage feats tile (bf16): 64 rows x 56 8B-chunks ----
    for (int idx = tid; idx < 64 * 56; idx += 256) {
        int row = idx / 56;
        int c   = idx - row * 56;
        int g   = base + row; if (g >= N_NODES) g = N_NODES - 1;
        ushort4v r;
        if (c < 16) {
            r = *(const ushort4v*)&feats_bf[(size_t)g * 64 + c * 4];
        } else if (c < 48) {
            float4 v = *(const float4*)&node[(size_t)g * NODE_DIM + (c - 16) * 4];
            r.x = f2bf(v.x); r.y = f2bf(v.y); r.z = f2bf(v.z); r.w = f2bf(v.w);
        } else {
            float4 v = *(const float4*)&glob[(c - 48) * 4];
            r.x = f2bf(v.x); r.y = f2bf(v.y); r.z = f2bf(v.z); r.w = f2bf(v.w);
        }
        *(ushort4v*)&sfeat[row][c * 4] = r;
    }
    __syncthreads();

    const int wave = tid >> 6;
    const int lane = tid & 63;
    const int lm   = lane & 15;    // fragment row / output col
    const int lk   = lane >> 4;    // k-group

    // ---- GEMM1: 16 n-tiles of 16 cols, K=224 ----
    f32x4 acc[16];
    #pragma unroll
    for (int nt = 0; nt < 16; ++nt) {
        float bv = b1[nt * 16 + lm];
        acc[nt] = (f32x4){bv, bv, bv, bv};
    }

    for (int k0 = 0; k0 < IN_DIM; k0 += 32) {
        short8 af = *(const short8*)&sfeat[wave * 16 + lm][k0 + lk * 8];
        #pragma unroll
        for (int nt = 0; nt < 16; ++nt) {
            short8 bf = *(const short8*)&W1T[(size_t)(nt * 16 + lm) * IN_DIM + k0 + lk * 8];
            acc[nt] = __builtin_amdgcn_mfma_f32_16x16x32_bf16(af, bf, acc[nt], 0, 0, 0);
        }
    }

    // ---- relu -> h LDS (bf16). C/D layout: col=l&15, row=(l>>4)*4+r ----
    #pragma unroll
    for (int nt = 0; nt < 16; ++nt) {
        #pragma unroll
        for (int r = 0; r < 4; ++r) {
            float v = acc[nt][r];
            v = fmaxf(v, 0.0f);
            sh[wave * 16 + lk * 4 + r][nt * 16 + lm] = f2bf(v);
        }
    }
    __syncthreads();

    // ---- GEMM2: 8 n-tiles, K=256 ----
    f32x4 acc2[8];
    #pragma unroll
    for (int nt = 0; nt < 8; ++nt) {
        float bv = b2[nt * 16 + lm];
        acc2[nt] = (f32x4){bv, bv, bv, bv};
    }

    for (int k0 = 0; k0 < HIDDEN; k0 += 32) {
        short8 af = *(const short8*)&sh[wave * 16 + lm][k0 + lk * 8];
        #pragma unroll
        for (int nt = 0; nt < 8; ++nt) {
            short8 bf = *(const short8*)&W2T[(size_t)(nt * 16 + lm) * HIDDEN + k0 + lk * 8];
            acc2[nt] = __builtin_amdgcn_mfma_f32_16x16x32_bf16(af, bf, acc2[nt], 0, 0, 0);
        }
    }

    // ---- store out fp32 ----
    #pragma unroll
    for (int nt = 0; nt < 8; ++nt) {
        #pragma unroll
        for (int r = 0; r < 4; ++r) {
            int grow = base + wave * 16 + lk * 4 + r;
            if (grow < N_NODES)
                out[(size_t)grow * OUT_DIM + nt * 16 + lm] = acc2[nt][r];
        }
    }
}

extern "C" void kernel_launch(void* const* d_in, const int* in_sizes, int n_in,
                              void* d_out, int out_size, void* d_ws, size_t ws_size,
                              hipStream_t stream) {
    const float* edge = (const float*)d_in[0];
    const int*   snd  = (const int*)  d_in[1];
    const int*   rcv  = (const int*)  d_in[2];
    const float* node = (const float*)d_in[3];
    const float* glob = (const float*)d_in[4];
    const float* W1   = (const float*)d_in[5];
    const float* b1   = (const float*)d_in[6];
    const float* W2   = (const float*)d_in[7];
    const float* b2   = (const float*)d_in[8];
    float* out = (float*)d_out;

    int* wsi = (int*)d_ws;
    unsigned short* feats_bf = (unsigned short*)(wsi + WS_FEATS_W);
    unsigned short* W1T      = (unsigned short*)(wsi + WS_W1T_W);
    unsigned short* W2T      = (unsigned short*)(wsi + WS_W2T_W);
    int* cnt  = wsi + WS_CNT_W;
    int* off  = wsi + WS_OFF_W;
    int* pos  = wsi + WS_POS_W;
    int* eids = wsi + WS_EIDS_W;
    int* bsum = wsi + WS_BSUM_W;

    hipMemsetAsync(cnt, 0, NCNT * sizeof(int), stream);

    wcvt_kernel<<<(IN_DIM * HIDDEN + HIDDEN * OUT_DIM + 255) / 256, 256, 0, stream>>>(
        W1, W2, W1T, W2T);

    const int eblocks = (N_EDGES + 255) / 256;
    hist_kernel  <<<eblocks, 256, 0, stream>>>(snd, rcv, cnt);
    scan1_kernel <<<NSCAN,   256, 0, stream>>>(cnt, off, bsum);
    scan23_kernel<<<NSCAN,   256, 0, stream>>>(off, bsum, pos);
    fill_kernel  <<<eblocks, 256, 0, stream>>>(snd, rcv, pos, eids);

    gather_kernel<<<(NCNT + 31) / 32, 256, 0, stream>>>(edge, off, eids, feats_bf);

    mlp_kernel<<<(N_NODES + 63) / 64, 256, 0, stream>>>(feats_bf, node, glob,
                                                        W1T, b1, W2T, b2, out);
}

// Round 5
// 581.191 us; speedup vs baseline: 2.7685x; 1.1711x over previous
//
#include <hip/hip_runtime.h>

#define N_NODES   100000
#define N_EDGES   1600000
#define EDGE_DIM  32
#define NODE_DIM  128
#define IN_DIM    224
#define HIDDEN    256
#define OUT_DIM   128
#define NCNT      (2 * N_NODES)
#define SCAN_BLK  1024
#define NSCAN     ((NCNT + SCAN_BLK - 1) / SCAN_BLK)   // 196

typedef float  f32x4    __attribute__((ext_vector_type(4)));
typedef short  short8   __attribute__((ext_vector_type(8)));
typedef unsigned short ushort4v __attribute__((ext_vector_type(4)));

// ---- BIG ws layout (words): sorted-rows pipeline (~117.8 MB) ----
#define B_SORT_W   0                          // u32[1.6M*16] = 102.4 MB
#define B_FEATS_W  25600000                   // ushort[100000*64]
#define B_W1T_W    (B_FEATS_W + 3200000)
#define B_W2T_W    (B_W1T_W + 28672)
#define B_CNT_W    (B_W2T_W + 16384)
#define B_OFF_W    (B_CNT_W + NCNT)
#define B_POS_W    (B_OFF_W + NCNT + 1)
#define B_BSUM_W   (B_POS_W + NCNT + 1)
#define B_TOTAL_W  (B_BSUM_W + NSCAN)

// ---- SMALL ws layout (words): round-4 eids fallback (~28.2 MB) ----
#define S_FEATS_W  0
#define S_W1T_W    3200000
#define S_W2T_W    3228672
#define S_CNT_W    3245056
#define S_OFF_W    (S_CNT_W + NCNT)
#define S_POS_W    (S_OFF_W + NCNT + 1)
#define S_EIDS_W   (S_POS_W + NCNT + 1)
#define S_BSUM_W   (S_EIDS_W + 2 * N_EDGES)

__device__ __forceinline__ unsigned short f2bf(float f) {
    unsigned int u = __float_as_uint(f);
    return (unsigned short)((u + 0x7fffu + ((u >> 16) & 1u)) >> 16);   // RNE
}

// ---------------------------------------------------------------------------
// Weight transpose + bf16 convert: W1T[n][k], W2T[o][k]
// ---------------------------------------------------------------------------
__global__ __launch_bounds__(256) void wcvt_kernel(
    const float* __restrict__ W1, const float* __restrict__ W2,
    unsigned short* __restrict__ W1T, unsigned short* __restrict__ W2T)
{
    int id = blockIdx.x * 256 + threadIdx.x;
    if (id < IN_DIM * HIDDEN) {
        int n = id / IN_DIM, k = id - n * IN_DIM;
        W1T[id] = f2bf(W1[(size_t)k * HIDDEN + n]);
    } else {
        int id2 = id - IN_DIM * HIDDEN;
        if (id2 < HIDDEN * OUT_DIM) {
            int o = id2 / HIDDEN, k = id2 - o * HIDDEN;
            W2T[id2] = f2bf(W2[(size_t)k * OUT_DIM + o]);
        }
    }
}

// ---------------------------------------------------------------------------
// Histogram
// ---------------------------------------------------------------------------
__global__ __launch_bounds__(256) void hist_kernel(
    const int* __restrict__ snd, const int* __restrict__ rcv, int* __restrict__ cnt)
{
    int e = blockIdx.x * 256 + threadIdx.x;
    if (e >= N_EDGES) return;
    atomicAdd(&cnt[rcv[e]], 1);
    atomicAdd(&cnt[N_NODES + snd[e]], 1);
}

// ---------------------------------------------------------------------------
// Scan pass 1
// ---------------------------------------------------------------------------
__global__ __launch_bounds__(256) void scan1_kernel(
    const int* __restrict__ cnt, int* __restrict__ off, int* __restrict__ bsum)
{
    __shared__ int ts[256];
    const int t = threadIdx.x;
    const int base = blockIdx.x * SCAN_BLK + t * 4;

    int v[4], s = 0;
    #pragma unroll
    for (int j = 0; j < 4; ++j) {
        int idx = base + j;
        v[j] = (idx < NCNT) ? cnt[idx] : 0;
        s += v[j];
    }
    ts[t] = s;
    __syncthreads();
    for (int d = 1; d < 256; d <<= 1) {
        int x = (t >= d) ? ts[t - d] : 0;
        __syncthreads();
        ts[t] += x;
        __syncthreads();
    }
    int run = ts[t] - s;
    #pragma unroll
    for (int j = 0; j < 4; ++j) {
        int idx = base + j;
        if (idx < NCNT) off[idx] = run;
        run += v[j];
    }
    if (t == 255) bsum[blockIdx.x] = ts[255];
}

// ---------------------------------------------------------------------------
// Scan pass 2+3 fused
// ---------------------------------------------------------------------------
__global__ __launch_bounds__(256) void scan23_kernel(
    int* __restrict__ off, const int* __restrict__ bsum, int* __restrict__ pos)
{
    __shared__ int ts[256];
    __shared__ int sboff;
    const int t = threadIdx.x;
    int v = (t < NSCAN) ? bsum[t] : 0;
    ts[t] = v;
    __syncthreads();
    for (int d = 1; d < 256; d <<= 1) {
        int x = (t >= d) ? ts[t - d] : 0;
        __syncthreads();
        ts[t] += x;
        __syncthreads();
    }
    if (t == (int)blockIdx.x) sboff = ts[t] - v;
    __syncthreads();
    const int bo = sboff;

    const int base = blockIdx.x * SCAN_BLK + t * 4;
    #pragma unroll
    for (int j = 0; j < 4; ++j) {
        int idx = base + j;
        if (idx < NCNT) {
            int o = off[idx] + bo;
            off[idx] = o;
            pos[idx] = o;
        }
    }
    if (blockIdx.x == 0 && t == 0) off[NCNT] = 2 * N_EDGES;
}

// ---------------------------------------------------------------------------
// fill_rows: one 16-lane group per edge. Lane 0 claims the sorted slot; the
// group writes the edge row as 32 bf16 = one full 64B line. Coalesced reads.
// ---------------------------------------------------------------------------
__global__ __launch_bounds__(256) void fill_rows_kernel(
    const float* __restrict__ edge,
    const int*   __restrict__ key,        // rcv or snd
    int*         __restrict__ pos,        // pos (+N_NODES for send)
    unsigned int* __restrict__ sorted,    // u32 view: row = 16 u32
    int slot_base)                        // 0 or N_EDGES
{
    int gid = blockIdx.x * 256 + threadIdx.x;
    int e = gid >> 4;
    if (e >= N_EDGES) return;
    int l = gid & 15;

    float2 v = *(const float2*)&edge[(size_t)e * EDGE_DIM + l * 2];
    unsigned int pk = (unsigned int)f2bf(v.x) | ((unsigned int)f2bf(v.y) << 16);

    int slot = 0;
    if (l == 0) slot = atomicAdd(&pos[key[e]], 1) - slot_base;
    slot = __shfl(slot, 0, 16);

    sorted[(size_t)slot * 16 + l] = pk;
}

// ---------------------------------------------------------------------------
// gather_rows: 16 lanes per node sum a CONTIGUOUS run of sorted bf16 rows.
// ---------------------------------------------------------------------------
__global__ __launch_bounds__(256) void gather_rows_kernel(
    const unsigned int* __restrict__ sorted,
    const int* __restrict__ off,          // off (+N_NODES for send)
    unsigned short* __restrict__ feats_bf,
    int slot_base, int col_base)
{
    int gid = blockIdx.x * 256 + threadIdx.x;
    int n = gid >> 4;
    if (n >= N_NODES) return;
    int l = gid & 15;

    int s = off[n] - slot_base, e = off[n + 1] - slot_base;
    float ax = 0.f, ay = 0.f;
    for (int i = s; i < e; ++i) {
        unsigned int u = sorted[(size_t)i * 16 + l];
        ax += __uint_as_float(u << 16);
        ay += __uint_as_float(u & 0xffff0000u);
    }
    unsigned int pk = (unsigned int)f2bf(ax) | ((unsigned int)f2bf(ay) << 16);
    *(unsigned int*)&feats_bf[(size_t)n * 64 + col_base + l * 2] = pk;
}

// ---------------------------------------------------------------------------
// Fallback (small ws): round-4 eids fill + random gather
// ---------------------------------------------------------------------------
__global__ __launch_bounds__(256) void fill_kernel(
    const int* __restrict__ snd, const int* __restrict__ rcv,
    int* __restrict__ pos, int* __restrict__ eids)
{
    int e = blockIdx.x * 256 + threadIdx.x;
    if (e >= N_EDGES) return;
    int p = atomicAdd(&pos[rcv[e]], 1);
    eids[p] = e;
    int q = atomicAdd(&pos[N_NODES + snd[e]], 1);
    eids[q] = e;
}

__global__ __launch_bounds__(256) void gather_kernel(
    const float* __restrict__ edge,
    const int*   __restrict__ off,
    const int*   __restrict__ eids,
    unsigned short* __restrict__ feats_bf)
{
    int seg = blockIdx.x * 32 + (threadIdx.x >> 3);
    if (seg >= NCNT) return;
    const int sub = threadIdx.x & 7;

    int s = off[seg], e = off[seg + 1];
    float4 a = make_float4(0.f, 0.f, 0.f, 0.f);
    for (int i = s; i < e; ++i) {
        int eid = eids[i];
        float4 v = *(const float4*)&edge[(size_t)eid * EDGE_DIM + sub * 4];
        a.x += v.x; a.y += v.y; a.z += v.z; a.w += v.w;
    }
    int nodeI = (seg < N_NODES) ? seg : (seg - N_NODES);
    int colB  = (seg < N_NODES) ? 0 : 32;
    ushort4v r;
    r.x = f2bf(a.x); r.y = f2bf(a.y); r.z = f2bf(a.z); r.w = f2bf(a.w);
    *(ushort4v*)&feats_bf[(size_t)nodeI * 64 + colB + sub * 4] = r;
}

// ---------------------------------------------------------------------------
// MFMA MLP: 64 nodes/block, 4 waves (unchanged from round 4)
// ---------------------------------------------------------------------------
#define SFP 232
#define SHP 264

__global__ __launch_bounds__(256) void mlp_kernel(
    const unsigned short* __restrict__ feats_bf,
    const float* __restrict__ node,
    const float* __restrict__ glob,
    const unsigned short* __restrict__ W1T,
    const float* __restrict__ b1,
    const unsigned short* __restrict__ W2T,
    const float* __restrict__ b2,
    float*       __restrict__ out)
{
    __shared__ unsigned short sfeat[64][SFP];
    __shared__ unsigned short sh[64][SHP];

    const int tid  = threadIdx.x;
    const int base = blockIdx.x * 64;

    for (int idx = tid; idx < 64 * 56; idx += 256) {
        int row = idx / 56;
        int c   = idx - row * 56;
        int g   = base + row; if (g >= N_NODES) g = N_NODES - 1;
        ushort4v r;
        if (c < 16) {
            r = *(const ushort4v*)&feats_bf[(size_t)g * 64 + c * 4];
        } else if (c < 48) {
            float4 v = *(const float4*)&node[(size_t)g * NODE_DIM + (c - 16) * 4];
            r.x = f2bf(v.x); r.y = f2bf(v.y); r.z = f2bf(v.z); r.w = f2bf(v.w);
        } else {
            float4 v = *(const float4*)&glob[(c - 48) * 4];
            r.x = f2bf(v.x); r.y = f2bf(v.y); r.z = f2bf(v.z); r.w = f2bf(v.w);
        }
        *(ushort4v*)&sfeat[row][c * 4] = r;
    }
    __syncthreads();

    const int wave = tid >> 6;
    const int lane = tid & 63;
    const int lm   = lane & 15;
    const int lk   = lane >> 4;

    f32x4 acc[16];
    #pragma unroll
    for (int nt = 0; nt < 16; ++nt) {
        float bv = b1[nt * 16 + lm];
        acc[nt] = (f32x4){bv, bv, bv, bv};
    }

    for (int k0 = 0; k0 < IN_DIM; k0 += 32) {
        short8 af = *(const short8*)&sfeat[wave * 16 + lm][k0 + lk * 8];
        #pragma unroll
        for (int nt = 0; nt < 16; ++nt) {
            short8 bf = *(const short8*)&W1T[(size_t)(nt * 16 + lm) * IN_DIM + k0 + lk * 8];
            acc[nt] = __builtin_amdgcn_mfma_f32_16x16x32_bf16(af, bf, acc[nt], 0, 0, 0);
        }
    }

    #pragma unroll
    for (int nt = 0; nt < 16; ++nt) {
        #pragma unroll
        for (int r = 0; r < 4; ++r) {
            float v = acc[nt][r];
            v = fmaxf(v, 0.0f);
            sh[wave * 16 + lk * 4 + r][nt * 16 + lm] = f2bf(v);
        }
    }
    __syncthreads();

    f32x4 acc2[8];
    #pragma unroll
    for (int nt = 0; nt < 8; ++nt) {
        float bv = b2[nt * 16 + lm];
        acc2[nt] = (f32x4){bv, bv, bv, bv};
    }

    for (int k0 = 0; k0 < HIDDEN; k0 += 32) {
        short8 af = *(const short8*)&sh[wave * 16 + lm][k0 + lk * 8];
        #pragma unroll
        for (int nt = 0; nt < 8; ++nt) {
            short8 bf = *(const short8*)&W2T[(size_t)(nt * 16 + lm) * HIDDEN + k0 + lk * 8];
            acc2[nt] = __builtin_amdgcn_mfma_f32_16x16x32_bf16(af, bf, acc2[nt], 0, 0, 0);
        }
    }

    #pragma unroll
    for (int nt = 0; nt < 8; ++nt) {
        #pragma unroll
        for (int r = 0; r < 4; ++r) {
            int grow = base + wave * 16 + lk * 4 + r;
            if (grow < N_NODES)
                out[(size_t)grow * OUT_DIM + nt * 16 + lm] = acc2[nt][r];
        }
    }
}

extern "C" void kernel_launch(void* const* d_in, const int* in_sizes, int n_in,
                              void* d_out, int out_size, void* d_ws, size_t ws_size,
                              hipStream_t stream) {
    const float* edge = (const float*)d_in[0];
    const int*   snd  = (const int*)  d_in[1];
    const int*   rcv  = (const int*)  d_in[2];
    const float* node = (const float*)d_in[3];
    const float* glob = (const float*)d_in[4];
    const float* W1   = (const float*)d_in[5];
    const float* b1   = (const float*)d_in[6];
    const float* W2   = (const float*)d_in[7];
    const float* b2   = (const float*)d_in[8];
    float* out = (float*)d_out;

    int* wsi = (int*)d_ws;
    const int eblocks = (N_EDGES + 255) / 256;
    const bool big = ws_size >= (size_t)B_TOTAL_W * 4;

    if (big) {
        unsigned int*   sorted   = (unsigned int*)(wsi + B_SORT_W);
        unsigned short* feats_bf = (unsigned short*)(wsi + B_FEATS_W);
        unsigned short* W1T      = (unsigned short*)(wsi + B_W1T_W);
        unsigned short* W2T      = (unsigned short*)(wsi + B_W2T_W);
        int* cnt  = wsi + B_CNT_W;
        int* off  = wsi + B_OFF_W;
        int* pos  = wsi + B_POS_W;
        int* bsum = wsi + B_BSUM_W;

        hipMemsetAsync(cnt, 0, NCNT * sizeof(int), stream);
        wcvt_kernel<<<(IN_DIM * HIDDEN + HIDDEN * OUT_DIM + 255) / 256, 256, 0, stream>>>(
            W1, W2, W1T, W2T);
        hist_kernel  <<<eblocks, 256, 0, stream>>>(snd, rcv, cnt);
        scan1_kernel <<<NSCAN,   256, 0, stream>>>(cnt, off, bsum);
        scan23_kernel<<<NSCAN,   256, 0, stream>>>(off, bsum, pos);

        const int fb = (N_EDGES * 16) / 256;       // 100000
        const int gb = (N_NODES * 16 + 255) / 256; // 6250
        // receivers
        fill_rows_kernel  <<<fb, 256, 0, stream>>>(edge, rcv, pos, sorted, 0);
        gather_rows_kernel<<<gb, 256, 0, stream>>>(sorted, off, feats_bf, 0, 0);
        // senders (reuse sorted buffer)
        fill_rows_kernel  <<<fb, 256, 0, stream>>>(edge, snd, pos + N_NODES, sorted, N_EDGES);
        gather_rows_kernel<<<gb, 256, 0, stream>>>(sorted, off + N_NODES, feats_bf, N_EDGES, 32);

        mlp_kernel<<<(N_NODES + 63) / 64, 256, 0, stream>>>(feats_bf, node, glob,
                                                            W1T, b1, W2T, b2, out);
    } else {
        unsigned short* feats_bf = (unsigned short*)(wsi + S_FEATS_W);
        unsigned short* W1T      = (unsigned short*)(wsi + S_W1T_W);
        unsigned short* W2T      = (unsigned short*)(wsi + S_W2T_W);
        int* cnt  = wsi + S_CNT_W;
        int* off  = wsi + S_OFF_W;
        int* pos  = wsi + S_POS_W;
        int* eids = wsi + S_EIDS_W;
        int* bsum = wsi + S_BSUM_W;

        hipMemsetAsync(cnt, 0, NCNT * sizeof(int), stream);
        wcvt_kernel<<<(IN_DIM * HIDDEN + HIDDEN * OUT_DIM + 255) / 256, 256, 0, stream>>>(
            W1, W2, W1T, W2T);
        hist_kernel  <<<eblocks, 256, 0, stream>>>(snd, rcv, cnt);
        scan1_kernel <<<NSCAN,   256, 0, stream>>>(cnt, off, bsum);
        scan23_kernel<<<NSCAN,   256, 0, stream>>>(off, bsum, pos);
        fill_kernel  <<<eblocks, 256, 0, stream>>>(snd, rcv, pos, eids);
        gather_kernel<<<(NCNT + 31) / 32, 256, 0, stream>>>(edge, off, eids, feats_bf);

        mlp_kernel<<<(N_NODES + 63) / 64, 256, 0, stream>>>(feats_bf, node, glob,
                                                            W1T, b1, W2T, b2, out);
    }
}

// Round 6
// 464.967 us; speedup vs baseline: 3.4605x; 1.2500x over previous
//
#include <hip/hip_runtime.h>

#define N_NODES   100000
#define N_EDGES   1600000
#define EDGE_DIM  32
#define NODE_DIM  128
#define K1        192    // rec32 + send32 + node128 (glob folded into b1_eff)
#define HIDDEN    256
#define OUT_DIM   128
#define NCNT      (2 * N_NODES)
#define SCAN_BLK  1024
#define NSCAN     ((NCNT + SCAN_BLK - 1) / SCAN_BLK)   // 196

typedef float  f32x4   __attribute__((ext_vector_type(4)));
typedef short  short8  __attribute__((ext_vector_type(8)));
typedef unsigned short ushort8 __attribute__((ext_vector_type(8)));
typedef unsigned short ushort4v __attribute__((ext_vector_type(4)));

// ---- BIG ws layout (words): sorted-rows pipeline (~117.8 MB) ----
#define B_SORT_W   0                          // u32[1.6M*16] = 102.4 MB
#define B_FEATS_W  25600000                   // ushort[100000*64] = 12.8 MB
#define B_W1T_W    (B_FEATS_W + 3200000)      // ushort[256*192]
#define B_W2T_W    (B_W1T_W + 24576)          // ushort[128*256]
#define B_B1E_W    (B_W2T_W + 16384)          // float[256]
#define B_CNT_W    (B_B1E_W + 256)
#define B_OFF_W    (B_CNT_W + NCNT)
#define B_POS_W    (B_OFF_W + NCNT + 1)
#define B_BSUM_W   (B_POS_W + NCNT + 1)
#define B_TOTAL_W  (B_BSUM_W + NSCAN)

// ---- SMALL ws layout (words): eids fallback (~28.2 MB) ----
#define S_FEATS_W  0
#define S_W1T_W    3200000
#define S_W2T_W    (S_W1T_W + 24576)
#define S_B1E_W    (S_W2T_W + 16384)
#define S_CNT_W    (S_B1E_W + 256)
#define S_OFF_W    (S_CNT_W + NCNT)
#define S_POS_W    (S_OFF_W + NCNT + 1)
#define S_EIDS_W   (S_POS_W + NCNT + 1)
#define S_BSUM_W   (S_EIDS_W + 2 * N_EDGES)

__device__ __forceinline__ unsigned short f2bf(float f) {
    unsigned int u = __float_as_uint(f);
    return (unsigned short)((u + 0x7fffu + ((u >> 16) & 1u)) >> 16);   // RNE
}

// ---------------------------------------------------------------------------
// Weight prep: W1T[n][k] (k<192), W2T[o][k], b1_eff = b1 + glob @ W1[192:224]
// ---------------------------------------------------------------------------
__global__ __launch_bounds__(256) void wcvt_kernel(
    const float* __restrict__ W1, const float* __restrict__ W2,
    const float* __restrict__ b1, const float* __restrict__ glob,
    unsigned short* __restrict__ W1T, unsigned short* __restrict__ W2T,
    float* __restrict__ b1e)
{
    int id = blockIdx.x * 256 + threadIdx.x;
    if (id < K1 * HIDDEN) {                              // 49152
        int n = id / K1, k = id - n * K1;
        W1T[id] = f2bf(W1[(size_t)k * HIDDEN + n]);
    } else if (id < K1 * HIDDEN + HIDDEN * OUT_DIM) {    // +32768
        int id2 = id - K1 * HIDDEN;
        int o = id2 / HIDDEN, k = id2 - o * HIDDEN;
        W2T[id2] = f2bf(W2[(size_t)k * OUT_DIM + o]);
    } else if (id < K1 * HIDDEN + HIDDEN * OUT_DIM + HIDDEN) {
        int n = id - (K1 * HIDDEN + HIDDEN * OUT_DIM);
        float s = b1[n];
        #pragma unroll
        for (int j = 0; j < 32; ++j)
            s += glob[j] * W1[(size_t)(K1 + j) * HIDDEN + n];
        b1e[n] = s;
    }
}

// ---------------------------------------------------------------------------
// Histogram
// ---------------------------------------------------------------------------
__global__ __launch_bounds__(256) void hist_kernel(
    const int* __restrict__ snd, const int* __restrict__ rcv, int* __restrict__ cnt)
{
    int e = blockIdx.x * 256 + threadIdx.x;
    if (e >= N_EDGES) return;
    atomicAdd(&cnt[rcv[e]], 1);
    atomicAdd(&cnt[N_NODES + snd[e]], 1);
}

// ---------------------------------------------------------------------------
// Scan pass 1
// ---------------------------------------------------------------------------
__global__ __launch_bounds__(256) void scan1_kernel(
    const int* __restrict__ cnt, int* __restrict__ off, int* __restrict__ bsum)
{
    __shared__ int ts[256];
    const int t = threadIdx.x;
    const int base = blockIdx.x * SCAN_BLK + t * 4;

    int v[4], s = 0;
    #pragma unroll
    for (int j = 0; j < 4; ++j) {
        int idx = base + j;
        v[j] = (idx < NCNT) ? cnt[idx] : 0;
        s += v[j];
    }
    ts[t] = s;
    __syncthreads();
    for (int d = 1; d < 256; d <<= 1) {
        int x = (t >= d) ? ts[t - d] : 0;
        __syncthreads();
        ts[t] += x;
        __syncthreads();
    }
    int run = ts[t] - s;
    #pragma unroll
    for (int j = 0; j < 4; ++j) {
        int idx = base + j;
        if (idx < NCNT) off[idx] = run;
        run += v[j];
    }
    if (t == 255) bsum[blockIdx.x] = ts[255];
}

// ---------------------------------------------------------------------------
// Scan pass 2+3 fused
// ---------------------------------------------------------------------------
__global__ __launch_bounds__(256) void scan23_kernel(
    int* __restrict__ off, const int* __restrict__ bsum, int* __restrict__ pos)
{
    __shared__ int ts[256];
    __shared__ int sboff;
    const int t = threadIdx.x;
    int v = (t < NSCAN) ? bsum[t] : 0;
    ts[t] = v;
    __syncthreads();
    for (int d = 1; d < 256; d <<= 1) {
        int x = (t >= d) ? ts[t - d] : 0;
        __syncthreads();
        ts[t] += x;
        __syncthreads();
    }
    if (t == (int)blockIdx.x) sboff = ts[t] - v;
    __syncthreads();
    const int bo = sboff;

    const int base = blockIdx.x * SCAN_BLK + t * 4;
    #pragma unroll
    for (int j = 0; j < 4; ++j) {
        int idx = base + j;
        if (idx < NCNT) {
            int o = off[idx] + bo;
            off[idx] = o;
            pos[idx] = o;
        }
    }
    if (blockIdx.x == 0 && t == 0) off[NCNT] = 2 * N_EDGES;
}

// ---------------------------------------------------------------------------
// fill_rows: 16-lane group per edge; writes edge row as 32 bf16 (64B line)
// ---------------------------------------------------------------------------
__global__ __launch_bounds__(256) void fill_rows_kernel(
    const float* __restrict__ edge,
    const int*   __restrict__ key,
    int*         __restrict__ pos,
    unsigned int* __restrict__ sorted,
    int slot_base)
{
    int gid = blockIdx.x * 256 + threadIdx.x;
    int e = gid >> 4;
    if (e >= N_EDGES) return;
    int l = gid & 15;

    float2 v = *(const float2*)&edge[(size_t)e * EDGE_DIM + l * 2];
    unsigned int pk = (unsigned int)f2bf(v.x) | ((unsigned int)f2bf(v.y) << 16);

    int slot = 0;
    if (l == 0) slot = atomicAdd(&pos[key[e]], 1) - slot_base;
    slot = __shfl(slot, 0, 16);

    sorted[(size_t)slot * 16 + l] = pk;
}

// ---------------------------------------------------------------------------
// gather_rows: 16 lanes per node sum a contiguous run of sorted bf16 rows
// ---------------------------------------------------------------------------
__global__ __launch_bounds__(256) void gather_rows_kernel(
    const unsigned int* __restrict__ sorted,
    const int* __restrict__ off,
    unsigned short* __restrict__ feats_bf,
    int slot_base, int col_base)
{
    int gid = blockIdx.x * 256 + threadIdx.x;
    int n = gid >> 4;
    if (n >= N_NODES) return;
    int l = gid & 15;

    int s = off[n] - slot_base, e = off[n + 1] - slot_base;
    float ax = 0.f, ay = 0.f;
    for (int i = s; i < e; ++i) {
        unsigned int u = sorted[(size_t)i * 16 + l];
        ax += __uint_as_float(u << 16);
        ay += __uint_as_float(u & 0xffff0000u);
    }
    unsigned int pk = (unsigned int)f2bf(ax) | ((unsigned int)f2bf(ay) << 16);
    *(unsigned int*)&feats_bf[(size_t)n * 64 + col_base + l * 2] = pk;
}

// ---------------------------------------------------------------------------
// Fallback (small ws): eids fill + random gather
// ---------------------------------------------------------------------------
__global__ __launch_bounds__(256) void fill_kernel(
    const int* __restrict__ snd, const int* __restrict__ rcv,
    int* __restrict__ pos, int* __restrict__ eids)
{
    int e = blockIdx.x * 256 + threadIdx.x;
    if (e >= N_EDGES) return;
    int p = atomicAdd(&pos[rcv[e]], 1);
    eids[p] = e;
    int q = atomicAdd(&pos[N_NODES + snd[e]], 1);
    eids[q] = e;
}

__global__ __launch_bounds__(256) void gather_kernel(
    const float* __restrict__ edge,
    const int*   __restrict__ off,
    const int*   __restrict__ eids,
    unsigned short* __restrict__ feats_bf)
{
    int seg = blockIdx.x * 32 + (threadIdx.x >> 3);
    if (seg >= NCNT) return;
    const int sub = threadIdx.x & 7;

    int s = off[seg], e = off[seg + 1];
    float4 a = make_float4(0.f, 0.f, 0.f, 0.f);
    for (int i = s; i < e; ++i) {
        int eid = eids[i];
        float4 v = *(const float4*)&edge[(size_t)eid * EDGE_DIM + sub * 4];
        a.x += v.x; a.y += v.y; a.z += v.z; a.w += v.w;
    }
    int nodeI = (seg < N_NODES) ? seg : (seg - N_NODES);
    int colB  = (seg < N_NODES) ? 0 : 32;
    ushort4v r;
    r.x = f2bf(a.x); r.y = f2bf(a.y); r.z = f2bf(a.z); r.w = f2bf(a.w);
    *(ushort4v*)&feats_bf[(size_t)nodeI * 64 + colB + sub * 4] = r;
}

// ---------------------------------------------------------------------------
// Fused GEMM1+GEMM2: 64 nodes/block, 512 threads (8 waves).
// Wave w: GEMM1 h-cols [32w,32w+32) (W1 frags in regs), GEMM2 out-cols
// [16w,16w+16) (W2 frags in regs). A and h in XOR-swizzled LDS (bf16).
// LDS = 24 KB (sA) + 32 KB (sH) = 56 KB -> 2 blocks/CU.
// ---------------------------------------------------------------------------
__global__ __launch_bounds__(512) void gemm12_kernel(
    const unsigned short* __restrict__ feats_bf,
    const float* __restrict__ node,
    const unsigned short* __restrict__ W1T,
    const float* __restrict__ b1e,
    const unsigned short* __restrict__ W2T,
    const float* __restrict__ b2,
    float*       __restrict__ out)
{
    __shared__ unsigned short sA[64 * K1];       // 24 KB, 24 chunks/row, XOR-swz
    __shared__ unsigned short sH[64 * HIDDEN];   // 32 KB, 32 chunks/row, XOR-swz

    const int tid  = threadIdx.x;
    const int base = blockIdx.x * 64;

    // ---- stage A tile: 64 rows x 24 16B-chunks (feats_bf bf16 + node f32->bf16)
    for (int idx = tid; idx < 64 * 24; idx += 512) {
        int row = idx / 24;
        int c   = idx - row * 24;
        int g   = base + row; if (g >= N_NODES) g = N_NODES - 1;
        ushort8 r;
        if (c < 8) {
            r = *(const ushort8*)&feats_bf[(size_t)g * 64 + c * 8];
        } else {
            const float* np = &node[(size_t)g * NODE_DIM + (c - 8) * 8];
            float4 v0 = *(const float4*)np;
            float4 v1 = *(const float4*)(np + 4);
            r[0] = f2bf(v0.x); r[1] = f2bf(v0.y); r[2] = f2bf(v0.z); r[3] = f2bf(v0.w);
            r[4] = f2bf(v1.x); r[5] = f2bf(v1.y); r[6] = f2bf(v1.z); r[7] = f2bf(v1.w);
        }
        *(ushort8*)&sA[row * K1 + ((c ^ (row & 7)) << 3)] = r;
    }
    __syncthreads();

    const int wave = tid >> 6;
    const int lane = tid & 63;
    const int lm   = lane & 15;
    const int lk   = lane >> 4;

    // ---- W1 fragments in registers: 2 n-tiles x 6 k-steps ----
    short8 w1f[2][6];
    #pragma unroll
    for (int j = 0; j < 2; ++j) {
        int nt = 2 * wave + j;
        #pragma unroll
        for (int k = 0; k < 6; ++k)
            w1f[j][k] = *(const short8*)&W1T[(size_t)(nt * 16 + lm) * K1 + k * 32 + lk * 8];
    }

    f32x4 acc1[4][2];
    {
        float bv0 = b1e[(2 * wave) * 16 + lm];
        float bv1 = b1e[(2 * wave + 1) * 16 + lm];
        #pragma unroll
        for (int m = 0; m < 4; ++m) {
            acc1[m][0] = (f32x4){bv0, bv0, bv0, bv0};
            acc1[m][1] = (f32x4){bv1, bv1, bv1, bv1};
        }
    }

    // ---- GEMM1: K=192, 6 k-steps x 4 m-tiles x 2 n-tiles ----
    #pragma unroll
    for (int k = 0; k < 6; ++k) {
        #pragma unroll
        for (int m = 0; m < 4; ++m) {
            int row   = m * 16 + lm;
            int chunk = k * 4 + lk;
            short8 af = *(const short8*)&sA[row * K1 + ((chunk ^ (row & 7)) << 3)];
            acc1[m][0] = __builtin_amdgcn_mfma_f32_16x16x32_bf16(af, w1f[0][k], acc1[m][0], 0, 0, 0);
            acc1[m][1] = __builtin_amdgcn_mfma_f32_16x16x32_bf16(af, w1f[1][k], acc1[m][1], 0, 0, 0);
        }
    }

    // ---- relu -> sH (bf16, swizzled). C layout: col=lm, row=lk*4+r ----
    #pragma unroll
    for (int m = 0; m < 4; ++m) {
        #pragma unroll
        for (int j = 0; j < 2; ++j) {
            int col   = (2 * wave + j) * 16 + lm;
            int chunk = col >> 3;
            int cin   = col & 7;
            #pragma unroll
            for (int r = 0; r < 4; ++r) {
                int rowl = m * 16 + lk * 4 + r;
                float v = fmaxf(acc1[m][j][r], 0.0f);
                sH[rowl * HIDDEN + ((chunk ^ (rowl & 7)) << 3) + cin] = f2bf(v);
            }
        }
    }

    // ---- W2 fragments (loaded while waves converge on the barrier) ----
    short8 w2f[8];
    #pragma unroll
    for (int k = 0; k < 8; ++k)
        w2f[k] = *(const short8*)&W2T[(size_t)(wave * 16 + lm) * HIDDEN + k * 32 + lk * 8];

    f32x4 acc2[4];
    {
        float bv = b2[wave * 16 + lm];
        #pragma unroll
        for (int m = 0; m < 4; ++m) acc2[m] = (f32x4){bv, bv, bv, bv};
    }
    __syncthreads();

    // ---- GEMM2: K=256, 8 k-steps x 4 m-tiles x 1 n-tile ----
    #pragma unroll
    for (int k = 0; k < 8; ++k) {
        #pragma unroll
        for (int m = 0; m < 4; ++m) {
            int row   = m * 16 + lm;
            int chunk = k * 4 + lk;
            short8 hf = *(const short8*)&sH[row * HIDDEN + ((chunk ^ (row & 7)) << 3)];
            acc2[m] = __builtin_amdgcn_mfma_f32_16x16x32_bf16(hf, w2f[k], acc2[m], 0, 0, 0);
        }
    }

    // ---- store out fp32 ----
    #pragma unroll
    for (int m = 0; m < 4; ++m) {
        #pragma unroll
        for (int r = 0; r < 4; ++r) {
            int grow = base + m * 16 + lk * 4 + r;
            if (grow < N_NODES)
                out[(size_t)grow * OUT_DIM + wave * 16 + lm] = acc2[m][r];
        }
    }
}

extern "C" void kernel_launch(void* const* d_in, const int* in_sizes, int n_in,
                              void* d_out, int out_size, void* d_ws, size_t ws_size,
                              hipStream_t stream) {
    const float* edge = (const float*)d_in[0];
    const int*   snd  = (const int*)  d_in[1];
    const int*   rcv  = (const int*)  d_in[2];
    const float* node = (const float*)d_in[3];
    const float* glob = (const float*)d_in[4];
    const float* W1   = (const float*)d_in[5];
    const float* b1   = (const float*)d_in[6];
    const float* W2   = (const float*)d_in[7];
    const float* b2   = (const float*)d_in[8];
    float* out = (float*)d_out;

    int* wsi = (int*)d_ws;
    const int eblocks = (N_EDGES + 255) / 256;
    const int wblocks = (K1 * HIDDEN + HIDDEN * OUT_DIM + HIDDEN + 255) / 256;
    const bool big = ws_size >= (size_t)B_TOTAL_W * 4;

    if (big) {
        unsigned int*   sorted   = (unsigned int*)(wsi + B_SORT_W);
        unsigned short* feats_bf = (unsigned short*)(wsi + B_FEATS_W);
        unsigned short* W1T      = (unsigned short*)(wsi + B_W1T_W);
        unsigned short* W2T      = (unsigned short*)(wsi + B_W2T_W);
        float*          b1e      = (float*)(wsi + B_B1E_W);
        int* cnt  = wsi + B_CNT_W;
        int* off  = wsi + B_OFF_W;
        int* pos  = wsi + B_POS_W;
        int* bsum = wsi + B_BSUM_W;

        hipMemsetAsync(cnt, 0, NCNT * sizeof(int), stream);
        wcvt_kernel<<<wblocks, 256, 0, stream>>>(W1, W2, b1, glob, W1T, W2T, b1e);
        hist_kernel  <<<eblocks, 256, 0, stream>>>(snd, rcv, cnt);
        scan1_kernel <<<NSCAN,   256, 0, stream>>>(cnt, off, bsum);
        scan23_kernel<<<NSCAN,   256, 0, stream>>>(off, bsum, pos);

        const int fb = (N_EDGES * 16) / 256;
        const int gb = (N_NODES * 16 + 255) / 256;
        fill_rows_kernel  <<<fb, 256, 0, stream>>>(edge, rcv, pos, sorted, 0);
        gather_rows_kernel<<<gb, 256, 0, stream>>>(sorted, off, feats_bf, 0, 0);
        fill_rows_kernel  <<<fb, 256, 0, stream>>>(edge, snd, pos + N_NODES, sorted, N_EDGES);
        gather_rows_kernel<<<gb, 256, 0, stream>>>(sorted, off + N_NODES, feats_bf, N_EDGES, 32);

        gemm12_kernel<<<(N_NODES + 63) / 64, 512, 0, stream>>>(
            feats_bf, node, W1T, b1e, W2T, b2, out);
    } else {
        unsigned short* feats_bf = (unsigned short*)(wsi + S_FEATS_W);
        unsigned short* W1T      = (unsigned short*)(wsi + S_W1T_W);
        unsigned short* W2T      = (unsigned short*)(wsi + S_W2T_W);
        float*          b1e      = (float*)(wsi + S_B1E_W);
        int* cnt  = wsi + S_CNT_W;
        int* off  = wsi + S_OFF_W;
        int* pos  = wsi + S_POS_W;
        int* eids = wsi + S_EIDS_W;
        int* bsum = wsi + S_BSUM_W;

        hipMemsetAsync(cnt, 0, NCNT * sizeof(int), stream);
        wcvt_kernel<<<wblocks, 256, 0, stream>>>(W1, W2, b1, glob, W1T, W2T, b1e);
        hist_kernel  <<<eblocks, 256, 0, stream>>>(snd, rcv, cnt);
        scan1_kernel <<<NSCAN,   256, 0, stream>>>(cnt, off, bsum);
        scan23_kernel<<<NSCAN,   256, 0, stream>>>(off, bsum, pos);
        fill_kernel  <<<eblocks, 256, 0, stream>>>(snd, rcv, pos, eids);
        gather_kernel<<<(NCNT + 31) / 32, 256, 0, stream>>>(edge, off, eids, feats_bf);

        gemm12_kernel<<<(N_NODES + 63) / 64, 512, 0, stream>>>(
            feats_bf, node, W1T, b1e, W2T, b2, out);
    }
}